// Round 1
// baseline (1976.077 us; speedup 1.0000x reference)
//
#include <hip/hip_runtime.h>
#include <math.h>

#define ALPHA 0.2f

__device__ __forceinline__ float leaky(float x){ return x > 0.f ? x : ALPHA*x; }

static inline int cdiv(long a, long b){ return (int)((a + b - 1)/b); }

__global__ void k_zero_int(int* __restrict__ p, int n){
  int i = blockIdx.x*blockDim.x + threadIdx.x;
  if(i<n) p[i]=0;
}

__global__ void k_count(const int* __restrict__ dst, int nE, int* __restrict__ cnt){
  int i = blockIdx.x*blockDim.x + threadIdx.x;
  if(i<nE) atomicAdd(&cnt[dst[i]], 1);
}

__global__ void k_dinv(const int* __restrict__ cnt, float* __restrict__ dinv, int n){
  int i = blockIdx.x*blockDim.x + threadIdx.x;
  if(i<n) dinv[i] = rsqrtf((float)(cnt[i]+1));
}

// out[r][c] = leaky( sum_k X[r][k]*W[k][c] + b[c] ), K=128, 64 cols, 4 rows/block
__global__ void k_linear128(const float* __restrict__ X, const float* __restrict__ W,
                            const float* __restrict__ b, float* __restrict__ out, int rows){
  __shared__ float Wl[128*64];
  __shared__ float bl[64];
  int tid = threadIdx.x;
  #pragma unroll
  for(int i=0;i<32;i++) Wl[i*256+tid] = W[i*256+tid];
  if(tid<64) bl[tid]=b[tid];
  __syncthreads();
  int col = tid & 63;
  int row = blockIdx.x*4 + (tid>>6);
  if(row>=rows) return;
  const float* xr = X + (size_t)row*128;
  float acc = bl[col];
  #pragma unroll
  for(int k=0;k<128;k++) acc = fmaf(xr[k], Wl[k*64+col], acc);
  out[(size_t)row*64+col] = leaky(acc);
}

// out[r][c] = sum_k f(X[r][k])*W[k][c]   (f = leaky if LEAKY_IN), K=64
template<int LEAKY_IN>
__global__ void k_gemm64(const float* __restrict__ X, const float* __restrict__ W,
                         float* __restrict__ out, int rows){
  __shared__ float Wl[64*64];
  int tid = threadIdx.x;
  #pragma unroll
  for(int i=0;i<16;i++) Wl[i*256+tid]=W[i*256+tid];
  __syncthreads();
  int col = tid & 63;
  int row = blockIdx.x*4 + (tid>>6);
  if(row>=rows) return;
  const float* xr = X + (size_t)row*64;
  float acc = 0.f;
  #pragma unroll
  for(int k=0;k<64;k++){
    float xv = xr[k];
    if(LEAKY_IN) xv = leaky(xv);
    acc = fmaf(xv, Wl[k*64+col], acc);
  }
  out[(size_t)row*64+col]=acc;
}

// out[i][c] = b[c] + h2[i][c]*dinv[i]^2   (bias + self-loop contribution)
__global__ void k_init_self(const float* __restrict__ h2, const float* __restrict__ dinv,
                            const float* __restrict__ b, float* __restrict__ out, int n){
  int tid = blockIdx.x*blockDim.x + threadIdx.x;
  int i = tid>>6, c = tid&63;
  if(i<n){
    float dv = dinv[i];
    out[(size_t)i*64+c] = b[c] + h2[(size_t)i*64+c]*dv*dv;
  }
}

// one wave per edge: out[d][c] += h2[s][c] * dinv[s]*dinv[d]
__global__ void k_scatter(const int* __restrict__ src, const int* __restrict__ dst,
                          const float* __restrict__ h2, const float* __restrict__ dinv,
                          float* __restrict__ out, int nE){
  int tid = blockIdx.x*blockDim.x + threadIdx.x;
  int e = tid>>6, c = tid&63;
  if(e<nE){
    int s = src[e], d = dst[e];
    float w = dinv[s]*dinv[d];
    atomicAdd(&out[(size_t)d*64+c], h2[(size_t)s*64+c]*w);
  }
}

__global__ void k_copy_leaky(const float* __restrict__ in, float* __restrict__ out, int n){
  int i = blockIdx.x*blockDim.x + threadIdx.x;
  if(i<n) out[i] = leaky(in[i]);
}

// one wave per row: logits = leaky(Z[row]) @ Wc + bc, then log_softmax over 2 classes
__global__ void k_classifier(const float* __restrict__ Z, const float* __restrict__ Wc,
                             const float* __restrict__ bc, float* __restrict__ out, int rows){
  int tid = blockIdx.x*blockDim.x + threadIdx.x;
  int row = tid>>6, lane = tid&63;
  if(row>=rows) return;
  float zv = leaky(Z[(size_t)row*64+lane]);
  float a0 = zv * Wc[lane*2+0];
  float a1 = zv * Wc[lane*2+1];
  #pragma unroll
  for(int off=32; off; off>>=1){
    a0 += __shfl_down(a0, off);
    a1 += __shfl_down(a1, off);
  }
  if(lane==0){
    float l0 = a0 + bc[0], l1 = a1 + bc[1];
    float m  = fmaxf(l0,l1);
    float lse = m + logf(expf(l0-m)+expf(l1-m));
    out[(size_t)row*2+0] = l0 - lse;
    out[(size_t)row*2+1] = l1 - lse;
  }
}

extern "C" void kernel_launch(void* const* d_in, const int* in_sizes, int n_in,
                              void* d_out, int out_size, void* d_ws, size_t ws_size,
                              hipStream_t stream) {
  const float* x      = (const float*)d_in[0];
  const float* meta_x = (const float*)d_in[1];
  const int*   ei     = (const int*)d_in[2];
  const int*   mei    = (const int*)d_in[3];
  const float* W_lin  = (const float*)d_in[4];
  const float* b_lin  = (const float*)d_in[5];
  const float* W_meta = (const float*)d_in[6];
  const float* b_meta = (const float*)d_in[7];
  const float* Ws     = (const float*)d_in[8];
  const float* bs_    = (const float*)d_in[9];
  const float* W_mg   = (const float*)d_in[10];
  const float* b_mg   = (const float*)d_in[11];
  const float* W_cls  = (const float*)d_in[12];
  const float* b_cls  = (const float*)d_in[13];
  float* out = (float*)d_out;

  const int N  = in_sizes[0]/128;
  const int M  = in_sizes[1]/128;
  const int E  = in_sizes[2]/2;
  const int ME = in_sizes[3]/2;
  const int NM = N + M;

  // workspace layout
  char* ws = (char*)d_ws;
  size_t off = 0;
  auto alloc = [&](size_t bytes)->void*{ void* p = ws + off; off += (bytes + 255) & ~(size_t)255; return p; };
  float* zbuf  = (float*)alloc((size_t)NM*64*4);   // concat(leaky(h3), mh)
  float* outz  = (float*)alloc((size_t)NM*64*4);   // meta gcn accumulator
  float* hreg  = (float*)alloc((size_t)3*N*64*4);  // 3 rotating N x 64 buffers
  float* hA = hreg, *hB = hreg + (size_t)N*64, *hC = hreg + (size_t)2*N*64;
  float* z2 = hreg;                                 // alias: meta gemm output (fits in 76.8MB)
  int*   cnt_g  = (int*)  alloc((size_t)N*4);
  int*   cnt_m  = (int*)  alloc((size_t)NM*4);
  float* dinv_g = (float*)alloc((size_t)N*4);
  float* dinv_m = (float*)alloc((size_t)NM*4);
  (void)ws_size; (void)n_in; (void)out_size;

  const int B = 256;

  // degrees -> dinv (self-loop => deg = cnt+1)
  k_zero_int<<<cdiv(N,B),  B, 0, stream>>>(cnt_g, N);
  k_zero_int<<<cdiv(NM,B), B, 0, stream>>>(cnt_m, NM);
  k_count<<<cdiv(E,B),  B, 0, stream>>>(ei  + E,  E,  cnt_g);
  k_count<<<cdiv(ME,B), B, 0, stream>>>(mei + ME, ME, cnt_m);
  k_dinv<<<cdiv(N,B),  B, 0, stream>>>(cnt_g, dinv_g, N);
  k_dinv<<<cdiv(NM,B), B, 0, stream>>>(cnt_m, dinv_m, NM);

  // input linears (leaky fused)
  k_linear128<<<cdiv(N,4), B, 0, stream>>>(x,      W_lin,  b_lin,  hA,               N);
  k_linear128<<<cdiv(M,4), B, 0, stream>>>(meta_x, W_meta, b_meta, zbuf + (size_t)N*64, M);

  // 3 GCN layers on the main graph
  float* cin = hA; float* ctmp = hB; float* cg = hC;
  for(int l=0; l<3; ++l){
    const float* Wl = Ws + (size_t)l*64*64;
    if(l==0) k_gemm64<0><<<cdiv(N,4), B, 0, stream>>>(cin, Wl, ctmp, N);
    else     k_gemm64<1><<<cdiv(N,4), B, 0, stream>>>(cin, Wl, ctmp, N);
    k_init_self<<<cdiv((size_t)N*64,B), B, 0, stream>>>(ctmp, dinv_g, bs_ + (size_t)l*64, cg, N);
    k_scatter<<<cdiv((size_t)E*64,B), B, 0, stream>>>(ei, ei + E, ctmp, dinv_g, cg, E);
    float* nin = cg, *ntmp = cin, *ng = ctmp;
    cin = nin; ctmp = ntmp; cg = ng;
  }
  // cin now holds raw gcn output of layer 3; apply leaky into z[0:N]
  k_copy_leaky<<<cdiv((size_t)N*64,B), B, 0, stream>>>(cin, zbuf, N*64);

  // meta GCN over N+M nodes (z already activated)
  k_gemm64<0><<<cdiv(NM,4), B, 0, stream>>>(zbuf, W_mg, z2, NM);
  k_init_self<<<cdiv((size_t)NM*64,B), B, 0, stream>>>(z2, dinv_m, b_mg, outz, NM);
  k_scatter<<<cdiv((size_t)ME*64,B), B, 0, stream>>>(mei, mei + ME, z2, dinv_m, outz, ME);

  // classifier + log_softmax (leaky fused on input)
  k_classifier<<<cdiv((size_t)NM*64,B), B, 0, stream>>>(outz, W_cls, b_cls, out, NM);
}

// Round 2
// 1164.181 us; speedup vs baseline: 1.6974x; 1.6974x over previous
//
#include <hip/hip_runtime.h>
#include <math.h>

#define ALPHA 0.2f

__device__ __forceinline__ float leaky(float x){ return x > 0.f ? x : ALPHA*x; }
__device__ __forceinline__ float bcast(float v, int l){
  return __int_as_float(__builtin_amdgcn_readlane(__float_as_int(v), l));
}

static inline int cdiv(long a, long b){ return (int)((a + b - 1)/b); }

__global__ void k_zero_int(int* __restrict__ p, int n){
  int i = blockIdx.x*blockDim.x + threadIdx.x;
  if(i<n) p[i]=0;
}

__global__ void k_count(const int* __restrict__ dst, int nE, int* __restrict__ cnt){
  int i = blockIdx.x*blockDim.x + threadIdx.x;
  if(i<nE) atomicAdd(&cnt[dst[i]], 1);
}

__global__ void k_dinv(const int* __restrict__ cnt, float* __restrict__ dinv, int n){
  int i = blockIdx.x*blockDim.x + threadIdx.x;
  if(i<n) dinv[i] = rsqrtf((float)(cnt[i]+1));
}

// ---- exclusive scan (3 kernels, n <= 262144) ----
__global__ void k_scan1(const int* __restrict__ cnt, int* __restrict__ excl,
                        int* __restrict__ bsum, int n){
  __shared__ int s[256];
  int i = blockIdx.x*256 + threadIdx.x;
  int v = (i<n) ? cnt[i] : 0;
  s[threadIdx.x]=v; __syncthreads();
  #pragma unroll
  for(int off=1; off<256; off<<=1){
    int t = (threadIdx.x>=off) ? s[threadIdx.x-off] : 0;
    __syncthreads();
    s[threadIdx.x]+=t;
    __syncthreads();
  }
  if(i<n) excl[i] = s[threadIdx.x]-v;
  if(threadIdx.x==255) bsum[blockIdx.x]=s[255];
}

__global__ void k_scan2(int* __restrict__ bsum, int nb){
  __shared__ int s[1024];
  int v = (threadIdx.x<nb) ? bsum[threadIdx.x] : 0;
  s[threadIdx.x]=v; __syncthreads();
  #pragma unroll
  for(int off=1; off<1024; off<<=1){
    int t = (threadIdx.x>=off) ? s[threadIdx.x-off] : 0;
    __syncthreads();
    s[threadIdx.x]+=t;
    __syncthreads();
  }
  if(threadIdx.x<nb) bsum[threadIdx.x] = s[threadIdx.x]-v;  // exclusive
}

__global__ void k_scan3(int* __restrict__ excl, const int* __restrict__ bsum, int n){
  int i = blockIdx.x*256 + threadIdx.x;
  if(i<n && blockIdx.x>0) excl[i] += bsum[blockIdx.x];
}

// fill CSR: packed (src, weight) records per dst row
__global__ void k_fill(const int* __restrict__ src, const int* __restrict__ dst,
                       const float* __restrict__ dinv, const int* __restrict__ rowptr,
                       int* __restrict__ cur, int2* __restrict__ ce, int nE){
  int e = blockIdx.x*blockDim.x + threadIdx.x;
  if(e<nE){
    int s = src[e], d = dst[e];
    int pos = rowptr[d] + atomicAdd(&cur[d], 1);
    ce[pos] = make_int2(s, __float_as_int(dinv[s]*dinv[d]));
  }
}

// GEMM: out[r][c] = f(X[r]) . W[:,c]  — wave per row, W column in VGPRs,
// X row broadcast via readlane. K in {64,128}.
template<int K, int LEAKY_IN>
__global__ __launch_bounds__(256) void k_gemm(const float* __restrict__ X,
                                              const float* __restrict__ W,
                                              float* __restrict__ out, int rows){
  int lane = threadIdx.x & 63;
  int gw = (blockIdx.x*256 + threadIdx.x) >> 6;
  int nw = (gridDim.x*256) >> 6;
  float wcol[K];
  #pragma unroll
  for(int k=0;k<K;k++) wcol[k] = W[(size_t)k*64 + lane];
  for(int row = gw; row < rows; row += nw){
    const float* xr = X + (size_t)row*K;
    float a0=0.f, a1=0.f, a2=0.f, a3=0.f;
    #pragma unroll
    for(int kk=0; kk<K; kk+=64){
      float xv = xr[kk + lane];
      if(LEAKY_IN) xv = leaky(xv);
      #pragma unroll
      for(int k=0;k<64;k+=4){
        a0 = fmaf(bcast(xv, k+0), wcol[kk+k+0], a0);
        a1 = fmaf(bcast(xv, k+1), wcol[kk+k+1], a1);
        a2 = fmaf(bcast(xv, k+2), wcol[kk+k+2], a2);
        a3 = fmaf(bcast(xv, k+3), wcol[kk+k+3], a3);
      }
    }
    out[(size_t)row*64 + lane] = (a0+a1)+(a2+a3);
  }
}

// fused: out[i][c] = g( b[c] + h2[i][c]*dinv[i]^2 + sum_edges h2[s][c]*w )
template<int LEAKY_OUT>
__global__ void k_aggregate(const float* __restrict__ h2, const int* __restrict__ rowptr,
                            const int* __restrict__ cnt, const int2* __restrict__ ce,
                            const float* __restrict__ dinv, const float* __restrict__ b,
                            float* __restrict__ out, int n){
  int tid = blockIdx.x*blockDim.x + threadIdx.x;
  int i = tid>>6, c = tid&63;
  if(i>=n) return;
  float dv = dinv[i];
  float acc = b[c] + h2[(size_t)i*64+c]*dv*dv;
  int start = rowptr[i], m = cnt[i];
  if(m > 0){
    int2 p = ce[start];
    for(int j=0;j<m;j++){
      int2 nx = (j+1<m) ? ce[start+j+1] : p;   // 2-deep prefetch
      acc = fmaf(h2[(size_t)p.x*64+c], __int_as_float(p.y), acc);
      p = nx;
    }
  }
  out[(size_t)i*64+c] = LEAKY_OUT ? leaky(acc) : acc;
}

// one wave per row: logits = leaky(Z[row]) @ Wc + bc, then log_softmax over 2 classes
__global__ void k_classifier(const float* __restrict__ Z, const float* __restrict__ Wc,
                             const float* __restrict__ bc, float* __restrict__ out, int rows){
  int tid = blockIdx.x*blockDim.x + threadIdx.x;
  int row = tid>>6, lane = tid&63;
  if(row>=rows) return;
  float zv = leaky(Z[(size_t)row*64+lane]);
  float a0 = zv * Wc[lane*2+0];
  float a1 = zv * Wc[lane*2+1];
  #pragma unroll
  for(int off=32; off; off>>=1){
    a0 += __shfl_down(a0, off);
    a1 += __shfl_down(a1, off);
  }
  if(lane==0){
    float l0 = a0 + bc[0], l1 = a1 + bc[1];
    float m  = fmaxf(l0,l1);
    float lse = m + logf(expf(l0-m)+expf(l1-m));
    out[(size_t)row*2+0] = l0 - lse;
    out[(size_t)row*2+1] = l1 - lse;
  }
}

extern "C" void kernel_launch(void* const* d_in, const int* in_sizes, int n_in,
                              void* d_out, int out_size, void* d_ws, size_t ws_size,
                              hipStream_t stream) {
  const float* x      = (const float*)d_in[0];
  const float* meta_x = (const float*)d_in[1];
  const int*   ei     = (const int*)d_in[2];
  const int*   mei    = (const int*)d_in[3];
  const float* W_lin  = (const float*)d_in[4];
  const float* b_lin  = (const float*)d_in[5];
  const float* W_meta = (const float*)d_in[6];
  const float* b_meta = (const float*)d_in[7];
  const float* Ws     = (const float*)d_in[8];
  const float* bs_    = (const float*)d_in[9];
  const float* W_mg   = (const float*)d_in[10];
  const float* b_mg   = (const float*)d_in[11];
  const float* W_cls  = (const float*)d_in[12];
  const float* b_cls  = (const float*)d_in[13];
  float* out = (float*)d_out;

  const int N  = in_sizes[0]/128;
  const int M  = in_sizes[1]/128;
  const int E  = in_sizes[2]/2;
  const int ME = in_sizes[3]/2;
  const int NM = N + M;

  char* ws = (char*)d_ws;
  size_t off = 0;
  auto alloc = [&](size_t bytes)->void*{ void* p = ws + off; off += (bytes + 255) & ~(size_t)255; return p; };
  float* zbuf  = (float*)alloc((size_t)NM*64*4);            // concat(leaky(h3), mh)
  float* outz  = (float*)alloc((size_t)NM*64*4);            // meta gcn output
  size_t hwords = (size_t)(2*N > NM ? 2*N : NM)*64;
  float* hreg  = (float*)alloc(hwords*4);                   // 2 rotating N x 64 buffers
  float* hA = hreg, *hB = hreg + (size_t)N*64;
  float* z2 = hreg;                                          // alias: meta gemm output
  int2*  ce_g = (int2*)alloc((size_t)E*8);                  // packed CSR edges (main)
  int2*  ce_m = (int2*)alloc((size_t)ME*8);                 // packed CSR edges (meta)
  int* cnt_g    = (int*)alloc((size_t)N*4);
  int* cnt_m    = (int*)alloc((size_t)NM*4);
  int* cur_g    = (int*)alloc((size_t)N*4);
  int* cur_m    = (int*)alloc((size_t)NM*4);
  int* rowptr_g = (int*)alloc((size_t)N*4);
  int* rowptr_m = (int*)alloc((size_t)NM*4);
  int* bsumA    = (int*)alloc(1024*4);
  int* bsumB    = (int*)alloc(1024*4);
  float* dinv_g = (float*)alloc((size_t)N*4);
  float* dinv_m = (float*)alloc((size_t)NM*4);
  (void)ws_size; (void)n_in; (void)out_size;

  const int B = 256;
  const int nbA = cdiv(N, 256), nbB = cdiv(NM, 256);

  // degrees -> dinv (self-loop => deg = cnt+1)
  k_zero_int<<<cdiv(N,B),  B, 0, stream>>>(cnt_g, N);
  k_zero_int<<<cdiv(NM,B), B, 0, stream>>>(cnt_m, NM);
  k_zero_int<<<cdiv(N,B),  B, 0, stream>>>(cur_g, N);
  k_zero_int<<<cdiv(NM,B), B, 0, stream>>>(cur_m, NM);
  k_count<<<cdiv(E,B),  B, 0, stream>>>(ei  + E,  E,  cnt_g);
  k_count<<<cdiv(ME,B), B, 0, stream>>>(mei + ME, ME, cnt_m);
  k_dinv<<<cdiv(N,B),  B, 0, stream>>>(cnt_g, dinv_g, N);
  k_dinv<<<cdiv(NM,B), B, 0, stream>>>(cnt_m, dinv_m, NM);

  // CSR build (once; reused by all 3 main layers)
  k_scan1<<<nbA, 256, 0, stream>>>(cnt_g, rowptr_g, bsumA, N);
  k_scan2<<<1, 1024, 0, stream>>>(bsumA, nbA);
  k_scan3<<<nbA, 256, 0, stream>>>(rowptr_g, bsumA, N);
  k_scan1<<<nbB, 256, 0, stream>>>(cnt_m, rowptr_m, bsumB, NM);
  k_scan2<<<1, 1024, 0, stream>>>(bsumB, nbB);
  k_scan3<<<nbB, 256, 0, stream>>>(rowptr_m, bsumB, NM);
  k_fill<<<cdiv(E,B),  B, 0, stream>>>(ei,  ei  + E,  dinv_g, rowptr_g, cur_g, ce_g, E);
  k_fill<<<cdiv(ME,B), B, 0, stream>>>(mei, mei + ME, dinv_m, rowptr_m, cur_m, ce_m, ME);

  // input linears: h = leaky(x@W + b) — bias folded into aggregate? No: these
  // linears have their own bias+leaky per reference; do bias via extra row trick
  // is unnecessary — add bias by initializing with W augmented? Simpler: bias+leaky
  // applied in a tiny epilogue fused here via separate kernel-free path:
  // k_gemm has no bias; use aggregate-style epilogue. Instead: fold bias by
  // computing gemm then bias+leaky in classifier-style pass would cost a pass.
  // => do it with k_gemm into buffer, then fused bias+leaky is needed ONLY here,
  // so use a dedicated small kernel.
  k_gemm<128,0><<<1024, 256, 0, stream>>>(x,      W_lin,  hA,               N);
  k_gemm<128,0><<<1024, 256, 0, stream>>>(meta_x, W_meta, zbuf + (size_t)N*64, M);
  // bias + leaky in-place
  {
    struct L { static __global__ void k(float*, const float*, int); };
  }
  // (handled by k_biasleaky below)
  extern __global__ void k_biasleaky(float* __restrict__, const float* __restrict__, int);
  hipLaunchKernelGGL(k_biasleaky, dim3(cdiv((size_t)N*64,B)), dim3(B), 0, stream, hA, b_lin, N);
  hipLaunchKernelGGL(k_biasleaky, dim3(cdiv((size_t)M*64,B)), dim3(B), 0, stream, zbuf + (size_t)N*64, b_meta, M);

  // 3 GCN layers on the main graph (2 rotating buffers)
  float* cin = hA; float* tmp = hB;
  for(int l=0; l<3; ++l){
    const float* Wl = Ws + (size_t)l*64*64;
    const float* bl = bs_ + (size_t)l*64;
    if(l==0) k_gemm<64,0><<<1024, 256, 0, stream>>>(cin, Wl, tmp, N);
    else     k_gemm<64,1><<<1024, 256, 0, stream>>>(cin, Wl, tmp, N);
    if(l<2) k_aggregate<0><<<cdiv(N,4), B, 0, stream>>>(tmp, rowptr_g, cnt_g, ce_g, dinv_g, bl, cin, N);
    else    k_aggregate<1><<<cdiv(N,4), B, 0, stream>>>(tmp, rowptr_g, cnt_g, ce_g, dinv_g, bl, zbuf, N);
  }

  // meta GCN over N+M nodes (zbuf already activated)
  k_gemm<64,0><<<1024, 256, 0, stream>>>(zbuf, W_mg, z2, NM);
  k_aggregate<0><<<cdiv(NM,4), B, 0, stream>>>(z2, rowptr_m, cnt_m, ce_m, dinv_m, b_mg, outz, NM);

  // classifier + log_softmax (leaky fused on input)
  k_classifier<<<cdiv((size_t)NM*64,B), B, 0, stream>>>(outz, W_cls, b_cls, out, NM);
}

// bias + leaky, in place over [rows,64]
__global__ void k_biasleaky(float* __restrict__ h, const float* __restrict__ b, int rows){
  int tid = blockIdx.x*blockDim.x + threadIdx.x;
  int i = tid>>6, c = tid&63;
  if(i<rows) h[(size_t)i*64+c] = leaky(h[(size_t)i*64+c] + b[c]);
}

// Round 4
// 802.559 us; speedup vs baseline: 2.4622x; 1.4506x over previous
//
#include <hip/hip_runtime.h>
#include <math.h>

#define ALPHA 0.2f

__device__ __forceinline__ float leaky(float x){ return x > 0.f ? x : ALPHA*x; }
__device__ __forceinline__ float bcast(float v, int l){
  return __int_as_float(__builtin_amdgcn_readlane(__float_as_int(v), l));
}

static inline int cdiv(long a, long b){ return (int)((a + b - 1)/b); }

__global__ void k_zero_int(int* __restrict__ p, int n){
  int i = blockIdx.x*blockDim.x + threadIdx.x;
  if(i<n) p[i]=0;
}

__global__ void k_count(const int* __restrict__ dst, int nE, int* __restrict__ cnt){
  int i = blockIdx.x*blockDim.x + threadIdx.x;
  if(i<nE) atomicAdd(&cnt[dst[i]], 1);
}

__global__ void k_dinv(const int* __restrict__ cnt, float* __restrict__ dinv, int n){
  int i = blockIdx.x*blockDim.x + threadIdx.x;
  if(i<n) dinv[i] = rsqrtf((float)(cnt[i]+1));
}

// ---- exclusive scan over counts -> rowptr (n+1 entries) ----
__global__ void k_scan1(const int* __restrict__ cnt, int* __restrict__ excl,
                        int* __restrict__ bsum, int n){
  __shared__ int s[256];
  int i = blockIdx.x*256 + threadIdx.x;
  int v = (i<n) ? cnt[i] : 0;
  s[threadIdx.x]=v; __syncthreads();
  #pragma unroll
  for(int off=1; off<256; off<<=1){
    int t = (threadIdx.x>=off) ? s[threadIdx.x-off] : 0;
    __syncthreads();
    s[threadIdx.x]+=t;
    __syncthreads();
  }
  if(i<n) excl[i] = s[threadIdx.x]-v;
  if(threadIdx.x==255) bsum[blockIdx.x]=s[255];
}

__global__ void k_scan2(int* __restrict__ bsum, int nb){
  __shared__ int s[1024];
  int v = (threadIdx.x<nb) ? bsum[threadIdx.x] : 0;
  s[threadIdx.x]=v; __syncthreads();
  #pragma unroll
  for(int off=1; off<1024; off<<=1){
    int t = (threadIdx.x>=off) ? s[threadIdx.x-off] : 0;
    __syncthreads();
    s[threadIdx.x]+=t;
    __syncthreads();
  }
  if(threadIdx.x<nb) bsum[threadIdx.x] = s[threadIdx.x]-v;  // exclusive
}

__global__ void k_scan3(int* __restrict__ excl, const int* __restrict__ bsum,
                        int n, int total){
  int i = blockIdx.x*256 + threadIdx.x;
  if(i<n && blockIdx.x>0) excl[i] += bsum[blockIdx.x];
  if(blockIdx.x==0 && threadIdx.x==0) excl[n] = total;
}

// fill CSR: packed (src, weight) records per dst row
__global__ void k_fill(const int* __restrict__ src, const int* __restrict__ dst,
                       const float* __restrict__ dinv, const int* __restrict__ rowptr,
                       int* __restrict__ cur, int2* __restrict__ ce, int nE){
  int e = blockIdx.x*blockDim.x + threadIdx.x;
  if(e<nE){
    int s = src[e], d = dst[e];
    int pos = rowptr[d] + atomicAdd(&cur[d], 1);
    ce[pos] = make_int2(s, __float_as_int(dinv[s]*dinv[d]));
  }
}

// GEMM: out[r][c] = epi( f(X[r]) . W[:,c] )  — wave per row, W column in VGPRs,
// X row broadcast via readlane. K in {64,128}. EPI=1: += b[c], leaky.
template<int K, int LEAKY_IN, int EPI>
__global__ __launch_bounds__(256) void k_gemm(const float* __restrict__ X,
                                              const float* __restrict__ W,
                                              const float* __restrict__ b,
                                              float* __restrict__ out, int rows){
  int lane = threadIdx.x & 63;
  int gw = (blockIdx.x*256 + threadIdx.x) >> 6;
  int nw = (gridDim.x*256) >> 6;
  float wcol[K];
  #pragma unroll
  for(int k=0;k<K;k++) wcol[k] = W[(size_t)k*64 + lane];
  float bl = EPI ? b[lane] : 0.f;
  for(int row = gw; row < rows; row += nw){
    const float* xr = X + (size_t)row*K;
    float a0=0.f, a1=0.f, a2=0.f, a3=0.f;
    #pragma unroll
    for(int kk=0; kk<K; kk+=64){
      float xv = xr[kk + lane];
      if(LEAKY_IN) xv = leaky(xv);
      #pragma unroll
      for(int k=0;k<64;k+=4){
        a0 = fmaf(bcast(xv, k+0), wcol[kk+k+0], a0);
        a1 = fmaf(bcast(xv, k+1), wcol[kk+k+1], a1);
        a2 = fmaf(bcast(xv, k+2), wcol[kk+k+2], a2);
        a3 = fmaf(bcast(xv, k+3), wcol[kk+k+3], a3);
      }
    }
    float r = (a0+a1)+(a2+a3);
    if(EPI) r = leaky(r + bl);
    out[(size_t)row*64 + lane] = r;
  }
}

// fused: out[i][c] = g( b[c] + h2[i][c]*dinv[i]^2 + sum_edges h2[s][c]*w )
// one wave per node; 8-wide unrolled edge loop for memory-level parallelism
template<int LEAKY_OUT>
__global__ __launch_bounds__(256) void k_aggregate(const float* __restrict__ h2,
                            const int* __restrict__ rowptr,
                            const int2* __restrict__ ce,
                            const float* __restrict__ dinv, const float* __restrict__ b,
                            float* __restrict__ out, int n){
  int tid = blockIdx.x*blockDim.x + threadIdx.x;
  int i = tid>>6, c = tid&63;
  if(i>=n) return;
  float dv = dinv[i];
  int start = rowptr[i], end = rowptr[i+1];
  float a0 = b[c] + h2[(size_t)i*64+c]*dv*dv, a1=0.f, a2=0.f, a3=0.f;
  int j = start;
  for(; j+8 <= end; j += 8){
    int2 e0=ce[j+0], e1=ce[j+1], e2=ce[j+2], e3=ce[j+3];
    int2 e4=ce[j+4], e5=ce[j+5], e6=ce[j+6], e7=ce[j+7];
    float g0=h2[(size_t)e0.x*64+c], g1=h2[(size_t)e1.x*64+c];
    float g2=h2[(size_t)e2.x*64+c], g3=h2[(size_t)e3.x*64+c];
    float g4=h2[(size_t)e4.x*64+c], g5=h2[(size_t)e5.x*64+c];
    float g6=h2[(size_t)e6.x*64+c], g7=h2[(size_t)e7.x*64+c];
    a0 = fmaf(g0, __int_as_float(e0.y), a0);
    a1 = fmaf(g1, __int_as_float(e1.y), a1);
    a2 = fmaf(g2, __int_as_float(e2.y), a2);
    a3 = fmaf(g3, __int_as_float(e3.y), a3);
    a0 = fmaf(g4, __int_as_float(e4.y), a0);
    a1 = fmaf(g5, __int_as_float(e5.y), a1);
    a2 = fmaf(g6, __int_as_float(e6.y), a2);
    a3 = fmaf(g7, __int_as_float(e7.y), a3);
  }
  if(j < end){
    int m = end - j;
    int2 e0 = ce[j+0];
    int2 e1 = (m>1)?ce[j+1]:e0; int2 e2 = (m>2)?ce[j+2]:e0; int2 e3 = (m>3)?ce[j+3]:e0;
    int2 e4 = (m>4)?ce[j+4]:e0; int2 e5 = (m>5)?ce[j+5]:e0; int2 e6 = (m>6)?ce[j+6]:e0;
    float g0=h2[(size_t)e0.x*64+c];
    float g1=(m>1)?h2[(size_t)e1.x*64+c]:0.f;
    float g2=(m>2)?h2[(size_t)e2.x*64+c]:0.f;
    float g3=(m>3)?h2[(size_t)e3.x*64+c]:0.f;
    float g4=(m>4)?h2[(size_t)e4.x*64+c]:0.f;
    float g5=(m>5)?h2[(size_t)e5.x*64+c]:0.f;
    float g6=(m>6)?h2[(size_t)e6.x*64+c]:0.f;
    a0 = fmaf(g0, __int_as_float(e0.y), a0);
    if(m>1) a1 = fmaf(g1, __int_as_float(e1.y), a1);
    if(m>2) a2 = fmaf(g2, __int_as_float(e2.y), a2);
    if(m>3) a3 = fmaf(g3, __int_as_float(e3.y), a3);
    if(m>4) a0 = fmaf(g4, __int_as_float(e4.y), a0);
    if(m>5) a1 = fmaf(g5, __int_as_float(e5.y), a1);
    if(m>6) a2 = fmaf(g6, __int_as_float(e6.y), a2);
  }
  float acc = (a0+a1)+(a2+a3);
  out[(size_t)i*64+c] = LEAKY_OUT ? leaky(acc) : acc;
}

// one wave per row: logits = leaky(Z[row]) @ Wc + bc, then log_softmax over 2 classes
__global__ void k_classifier(const float* __restrict__ Z, const float* __restrict__ Wc,
                             const float* __restrict__ bc, float* __restrict__ out, int rows){
  int tid = blockIdx.x*blockDim.x + threadIdx.x;
  int row = tid>>6, lane = tid&63;
  if(row>=rows) return;
  float zv = leaky(Z[(size_t)row*64+lane]);
  float a0 = zv * Wc[lane*2+0];
  float a1 = zv * Wc[lane*2+1];
  #pragma unroll
  for(int off=32; off; off>>=1){
    a0 += __shfl_down(a0, off);
    a1 += __shfl_down(a1, off);
  }
  if(lane==0){
    float l0 = a0 + bc[0], l1 = a1 + bc[1];
    float m  = fmaxf(l0,l1);
    float lse = m + logf(expf(l0-m)+expf(l1-m));
    out[(size_t)row*2+0] = l0 - lse;
    out[(size_t)row*2+1] = l1 - lse;
  }
}

extern "C" void kernel_launch(void* const* d_in, const int* in_sizes, int n_in,
                              void* d_out, int out_size, void* d_ws, size_t ws_size,
                              hipStream_t stream) {
  const float* x      = (const float*)d_in[0];
  const float* meta_x = (const float*)d_in[1];
  const int*   ei     = (const int*)d_in[2];
  const int*   mei    = (const int*)d_in[3];
  const float* W_lin  = (const float*)d_in[4];
  const float* b_lin  = (const float*)d_in[5];
  const float* W_meta = (const float*)d_in[6];
  const float* b_meta = (const float*)d_in[7];
  const float* Ws     = (const float*)d_in[8];
  const float* bs_    = (const float*)d_in[9];
  const float* W_mg   = (const float*)d_in[10];
  const float* b_mg   = (const float*)d_in[11];
  const float* W_cls  = (const float*)d_in[12];
  const float* b_cls  = (const float*)d_in[13];
  float* out = (float*)d_out;

  const int N  = in_sizes[0]/128;
  const int M  = in_sizes[1]/128;
  const int E  = in_sizes[2]/2;
  const int ME = in_sizes[3]/2;
  const int NM = N + M;

  char* ws = (char*)d_ws;
  size_t off = 0;
  auto alloc = [&](size_t bytes)->void*{ void* p = ws + off; off += (bytes + 255) & ~(size_t)255; return p; };
  float* zbuf  = (float*)alloc((size_t)NM*64*4);            // concat(leaky(h3), mh)
  float* outz  = (float*)alloc((size_t)NM*64*4);            // meta gcn output
  size_t hwords = (size_t)(2*N > NM ? 2*N : NM)*64;
  float* hreg  = (float*)alloc(hwords*4);                   // 2 rotating N x 64 buffers
  float* hA = hreg, *hB = hreg + (size_t)N*64;
  float* z2 = hreg;                                          // alias: meta gemm output
  int2*  ce_g = (int2*)alloc((size_t)E*8);                  // packed CSR edges (main)
  int2*  ce_m = (int2*)alloc((size_t)ME*8);                 // packed CSR edges (meta)
  int* cnt_g    = (int*)alloc((size_t)N*4);
  int* cnt_m    = (int*)alloc((size_t)NM*4);
  int* cur_g    = (int*)alloc((size_t)N*4);
  int* cur_m    = (int*)alloc((size_t)NM*4);
  int* rowptr_g = (int*)alloc((size_t)(N+1)*4);
  int* rowptr_m = (int*)alloc((size_t)(NM+1)*4);
  int* bsumA    = (int*)alloc(1024*4);
  int* bsumB    = (int*)alloc(1024*4);
  float* dinv_g = (float*)alloc((size_t)N*4);
  float* dinv_m = (float*)alloc((size_t)NM*4);
  (void)ws_size; (void)n_in; (void)out_size;

  const int B = 256;
  const int nbA = cdiv(N, 256), nbB = cdiv(NM, 256);

  // degrees -> dinv (self-loop => deg = cnt+1)
  k_zero_int<<<cdiv(N,B),  B, 0, stream>>>(cnt_g, N);
  k_zero_int<<<cdiv(NM,B), B, 0, stream>>>(cnt_m, NM);
  k_zero_int<<<cdiv(N,B),  B, 0, stream>>>(cur_g, N);
  k_zero_int<<<cdiv(NM,B), B, 0, stream>>>(cur_m, NM);
  k_count<<<cdiv(E,B),  B, 0, stream>>>(ei  + E,  E,  cnt_g);
  k_count<<<cdiv(ME,B), B, 0, stream>>>(mei + ME, ME, cnt_m);
  k_dinv<<<cdiv(N,B),  B, 0, stream>>>(cnt_g, dinv_g, N);
  k_dinv<<<cdiv(NM,B), B, 0, stream>>>(cnt_m, dinv_m, NM);

  // CSR build (once; reused by all 3 main layers)
  k_scan1<<<nbA, 256, 0, stream>>>(cnt_g, rowptr_g, bsumA, N);
  k_scan2<<<1, 1024, 0, stream>>>(bsumA, nbA);
  k_scan3<<<nbA, 256, 0, stream>>>(rowptr_g, bsumA, N, E);
  k_scan1<<<nbB, 256, 0, stream>>>(cnt_m, rowptr_m, bsumB, NM);
  k_scan2<<<1, 1024, 0, stream>>>(bsumB, nbB);
  k_scan3<<<nbB, 256, 0, stream>>>(rowptr_m, bsumB, NM, ME);
  k_fill<<<cdiv(E,B),  B, 0, stream>>>(ei,  ei  + E,  dinv_g, rowptr_g, cur_g, ce_g, E);
  k_fill<<<cdiv(ME,B), B, 0, stream>>>(mei, mei + ME, dinv_m, rowptr_m, cur_m, ce_m, ME);

  // input linears: h = leaky(x@W + b), fused epilogue
  k_gemm<128,0,1><<<1024, 256, 0, stream>>>(x,      W_lin,  b_lin,  hA,                 N);
  k_gemm<128,0,1><<<1024, 256, 0, stream>>>(meta_x, W_meta, b_meta, zbuf + (size_t)N*64, M);

  // 3 GCN layers on the main graph (2 rotating buffers)
  float* cin = hA; float* tmp = hB;
  for(int l=0; l<3; ++l){
    const float* Wl = Ws + (size_t)l*64*64;
    const float* bl = bs_ + (size_t)l*64;
    if(l==0) k_gemm<64,0,0><<<2048, 256, 0, stream>>>(cin, Wl, nullptr, tmp, N);
    else     k_gemm<64,1,0><<<2048, 256, 0, stream>>>(cin, Wl, nullptr, tmp, N);
    if(l<2) k_aggregate<0><<<cdiv(N,4), B, 0, stream>>>(tmp, rowptr_g, ce_g, dinv_g, bl, cin, N);
    else    k_aggregate<1><<<cdiv(N,4), B, 0, stream>>>(tmp, rowptr_g, ce_g, dinv_g, bl, zbuf, N);
  }

  // meta GCN over N+M nodes (zbuf already activated)
  k_gemm<64,0,0><<<2048, 256, 0, stream>>>(zbuf, W_mg, nullptr, z2, NM);
  k_aggregate<0><<<cdiv(NM,4), B, 0, stream>>>(z2, rowptr_m, ce_m, dinv_m, b_mg, outz, NM);

  // classifier + log_softmax (leaky fused on input)
  k_classifier<<<cdiv((size_t)NM*64,B), B, 0, stream>>>(outz, W_cls, b_cls, out, NM);
}

// Round 7
// 758.679 us; speedup vs baseline: 2.6046x; 1.0578x over previous
//
#include <hip/hip_runtime.h>
#include <math.h>

#define ALPHA 0.2f

__device__ __forceinline__ float leaky(float x){ return x > 0.f ? x : ALPHA*x; }
__device__ __forceinline__ float bcast(float v, int l){
  return __int_as_float(__builtin_amdgcn_readlane(__float_as_int(v), l));
}
__device__ __forceinline__ int rdlane_i(int v, int l){
  return __builtin_amdgcn_readlane(v, l);
}

static inline int cdiv(long a, long b){ return (int)((a + b - 1)/b); }

// count both graphs' dst histograms in one launch
__global__ void k_count_dual(const int* __restrict__ dstA, int nA, int* __restrict__ cntA,
                             const int* __restrict__ dstB, int nB, int* __restrict__ cntB){
  int i = blockIdx.x*blockDim.x + threadIdx.x;
  if(i < nA) atomicAdd(&cntA[dstA[i]], 1);
  else if(i < nA + nB) atomicAdd(&cntB[dstB[i - nA]], 1);
}

__global__ void k_dinv_dual(const int* __restrict__ cntA, float* __restrict__ dinvA, int nA,
                            const int* __restrict__ cntB, float* __restrict__ dinvB, int nB){
  int i = blockIdx.x*blockDim.x + threadIdx.x;
  if(i < nA) dinvA[i] = rsqrtf((float)(cntA[i]+1));
  else if(i < nA + nB){ int j = i - nA; dinvB[j] = rsqrtf((float)(cntB[j]+1)); }
}

// ---- exclusive scan (dual-array, 3 stages) ----
__global__ void k_scan1_dual(const int* __restrict__ cntA, int* __restrict__ exA,
                             int* __restrict__ bsA, int nA, int nbA,
                             const int* __restrict__ cntB, int* __restrict__ exB,
                             int* __restrict__ bsB, int nB){
  const int* cnt; int* ex; int* bs; int n; int blk;
  if((int)blockIdx.x < nbA){ cnt=cntA; ex=exA; bs=bsA; n=nA; blk=blockIdx.x; }
  else                     { cnt=cntB; ex=exB; bs=bsB; n=nB; blk=blockIdx.x-nbA; }
  __shared__ int s[256];
  int i = blk*256 + threadIdx.x;
  int v = (i<n) ? cnt[i] : 0;
  s[threadIdx.x]=v; __syncthreads();
  #pragma unroll
  for(int off=1; off<256; off<<=1){
    int t = (threadIdx.x>=(unsigned)off) ? s[threadIdx.x-off] : 0;
    __syncthreads();
    s[threadIdx.x]+=t;
    __syncthreads();
  }
  if(i<n) ex[i] = s[threadIdx.x]-v;
  if(threadIdx.x==255) bs[blk]=s[255];
}

__global__ void k_scan2_dual(int* __restrict__ bsA, int nbA, int* __restrict__ bsB, int nbB){
  __shared__ int s[1024];
  {
    int v = ((int)threadIdx.x<nbA) ? bsA[threadIdx.x] : 0;
    s[threadIdx.x]=v; __syncthreads();
    #pragma unroll
    for(int off=1; off<1024; off<<=1){
      int t = (threadIdx.x>=(unsigned)off) ? s[threadIdx.x-off] : 0;
      __syncthreads();
      s[threadIdx.x]+=t;
      __syncthreads();
    }
    if((int)threadIdx.x<nbA) bsA[threadIdx.x] = s[threadIdx.x]-v;
    __syncthreads();
  }
  {
    int v = ((int)threadIdx.x<nbB) ? bsB[threadIdx.x] : 0;
    s[threadIdx.x]=v; __syncthreads();
    #pragma unroll
    for(int off=1; off<1024; off<<=1){
      int t = (threadIdx.x>=(unsigned)off) ? s[threadIdx.x-off] : 0;
      __syncthreads();
      s[threadIdx.x]+=t;
      __syncthreads();
    }
    if((int)threadIdx.x<nbB) bsB[threadIdx.x] = s[threadIdx.x]-v;
  }
}

__global__ void k_scan3_dual(int* __restrict__ exA, const int* __restrict__ bsA,
                             int nA, int nbA, int totA,
                             int* __restrict__ exB, const int* __restrict__ bsB,
                             int nB, int totB){
  int* ex; const int* bs; int n; int blk; int tot;
  if((int)blockIdx.x < nbA){ ex=exA; bs=bsA; n=nA; blk=blockIdx.x; tot=totA; }
  else                     { ex=exB; bs=bsB; n=nB; blk=blockIdx.x-nbA; tot=totB; }
  int i = blk*256 + threadIdx.x;
  if(i<n && blk>0) ex[i] += bs[blk];
  if(blk==0 && threadIdx.x==0) ex[n] = tot;
}

// fill both CSRs: record = src only (4B); weight recomputed in aggregate
__global__ void k_fill_dual(const int* __restrict__ eiA, int nA,
                            const int* __restrict__ rpA, int* __restrict__ curA,
                            int* __restrict__ ceA,
                            const int* __restrict__ eiB, int nB,
                            const int* __restrict__ rpB, int* __restrict__ curB,
                            int* __restrict__ ceB){
  int i = blockIdx.x*blockDim.x + threadIdx.x;
  if(i < nA){
    int s = eiA[i], d = eiA[nA + i];
    int pos = rpA[d] + atomicAdd(&curA[d], 1);
    ceA[pos] = s;
  } else if(i < nA + nB){
    int j = i - nA;
    int s = eiB[j], d = eiB[nB + j];
    int pos = rpB[d] + atomicAdd(&curB[d], 1);
    ceB[pos] = s;
  }
}

// GEMM: out[r][c] = epi( f(X[r]) . W[:,c] )  — wave per row, W column in VGPRs,
// X row broadcast via readlane. K in {64,128}. EPI=1: += b[c], leaky.
template<int K, int LEAKY_IN, int EPI>
__global__ __launch_bounds__(256) void k_gemm(const float* __restrict__ X,
                                              const float* __restrict__ W,
                                              const float* __restrict__ b,
                                              float* __restrict__ out, int rows){
  int lane = threadIdx.x & 63;
  int gw = (blockIdx.x*256 + threadIdx.x) >> 6;
  int nw = (gridDim.x*256) >> 6;
  float wcol[K];
  #pragma unroll
  for(int k=0;k<K;k++) wcol[k] = W[(size_t)k*64 + lane];
  float bl = EPI ? b[lane] : 0.f;
  for(int row = gw; row < rows; row += nw){
    const float* xr = X + (size_t)row*K;
    float a0=0.f, a1=0.f, a2=0.f, a3=0.f;
    #pragma unroll
    for(int kk=0; kk<K; kk+=64){
      float xv = xr[kk + lane];
      if(LEAKY_IN) xv = leaky(xv);
      #pragma unroll
      for(int k=0;k<64;k+=4){
        a0 = fmaf(bcast(xv, k+0), wcol[kk+k+0], a0);
        a1 = fmaf(bcast(xv, k+1), wcol[kk+k+1], a1);
        a2 = fmaf(bcast(xv, k+2), wcol[kk+k+2], a2);
        a3 = fmaf(bcast(xv, k+3), wcol[kk+k+3], a3);
      }
    }
    float r = (a0+a1)+(a2+a3);
    if(EPI) r = leaky(r + bl);
    out[(size_t)row*64 + lane] = r;
  }
}

// shared aggregate core: b[c] + h2[i][c]*dinv[i]^2 + sum_edges h2[s][c]*dinv[s]*dinv[i]
// per 8-edge batch, lanes 0..7 load consecutive ce + dinv; readlane-broadcast both;
// h2 gather row index becomes an SGPR (scalar base).
__device__ __forceinline__ float agg_acc(const float* __restrict__ h2,
                                         const int* __restrict__ rowptr,
                                         const int* __restrict__ ce,
                                         const float* __restrict__ dinv,
                                         const float* __restrict__ b,
                                         int i, int c){
  float dv = dinv[i];
  int start = rowptr[i], end = rowptr[i+1];
  float a0 = b[c] + h2[(size_t)i*64+c]*dv*dv, a1=0.f, a2=0.f, a3=0.f;
  int lane8 = c & 7;
  for(int j = start; j < end; j += 8){
    int idx = j + lane8; idx = (idx < end) ? idx : end-1;
    int sv = ce[idx];
    float dwv = dinv[sv];
    #pragma unroll
    for(int k=0;k<8;k+=4){
      int   s0 = rdlane_i(sv, k+0), s1 = rdlane_i(sv, k+1);
      int   s2 = rdlane_i(sv, k+2), s3 = rdlane_i(sv, k+3);
      float w0 = bcast(dwv, k+0), w1 = bcast(dwv, k+1);
      float w2 = bcast(dwv, k+2), w3 = bcast(dwv, k+3);
      float g0 = h2[(size_t)s0*64 + c];
      float g1 = h2[(size_t)s1*64 + c];
      float g2 = h2[(size_t)s2*64 + c];
      float g3 = h2[(size_t)s3*64 + c];
      w0 = (j+k+0 < end) ? w0*dv : 0.f;
      w1 = (j+k+1 < end) ? w1*dv : 0.f;
      w2 = (j+k+2 < end) ? w2*dv : 0.f;
      w3 = (j+k+3 < end) ? w3*dv : 0.f;
      a0 = fmaf(g0, w0, a0);
      a1 = fmaf(g1, w1, a1);
      a2 = fmaf(g2, w2, a2);
      a3 = fmaf(g3, w3, a3);
    }
  }
  return (a0+a1)+(a2+a3);
}

// fused GCN aggregate
template<int LEAKY_OUT>
__global__ __launch_bounds__(256) void k_aggregate(const float* __restrict__ h2,
                            const int* __restrict__ rowptr,
                            const int* __restrict__ ce,
                            const float* __restrict__ dinv, const float* __restrict__ b,
                            float* __restrict__ out, int n){
  int tid = blockIdx.x*blockDim.x + threadIdx.x;
  int i = tid>>6, c = tid&63;
  if(i>=n) return;
  float acc = agg_acc(h2, rowptr, ce, dinv, b, i, c);
  out[(size_t)i*64+c] = LEAKY_OUT ? leaky(acc) : acc;
}

// meta aggregate + classifier + log_softmax fused: out[i][0..1]
__global__ __launch_bounds__(256) void k_agg_cls(const float* __restrict__ h2,
                            const int* __restrict__ rowptr,
                            const int* __restrict__ ce,
                            const float* __restrict__ dinv, const float* __restrict__ b,
                            const float* __restrict__ Wc, const float* __restrict__ bc,
                            float* __restrict__ out, int n){
  int tid = blockIdx.x*blockDim.x + threadIdx.x;
  int i = tid>>6, c = tid&63;
  if(i>=n) return;
  float acc = agg_acc(h2, rowptr, ce, dinv, b, i, c);
  float zv = leaky(acc);
  float s0 = zv * Wc[c*2+0];
  float s1 = zv * Wc[c*2+1];
  #pragma unroll
  for(int off=32; off; off>>=1){
    s0 += __shfl_down(s0, off);
    s1 += __shfl_down(s1, off);
  }
  if(c==0){
    float l0 = s0 + bc[0], l1 = s1 + bc[1];
    float m  = fmaxf(l0,l1);
    float lse = m + logf(expf(l0-m)+expf(l1-m));
    out[(size_t)i*2+0] = l0 - lse;
    out[(size_t)i*2+1] = l1 - lse;
  }
}

extern "C" void kernel_launch(void* const* d_in, const int* in_sizes, int n_in,
                              void* d_out, int out_size, void* d_ws, size_t ws_size,
                              hipStream_t stream) {
  const float* x      = (const float*)d_in[0];
  const float* meta_x = (const float*)d_in[1];
  const int*   ei     = (const int*)d_in[2];
  const int*   mei    = (const int*)d_in[3];
  const float* W_lin  = (const float*)d_in[4];
  const float* b_lin  = (const float*)d_in[5];
  const float* W_meta = (const float*)d_in[6];
  const float* b_meta = (const float*)d_in[7];
  const float* Ws     = (const float*)d_in[8];
  const float* bs_    = (const float*)d_in[9];
  const float* W_mg   = (const float*)d_in[10];
  const float* b_mg   = (const float*)d_in[11];
  const float* W_cls  = (const float*)d_in[12];
  const float* b_cls  = (const float*)d_in[13];
  float* out = (float*)d_out;

  const int N  = in_sizes[0]/128;
  const int M  = in_sizes[1]/128;
  const int E  = in_sizes[2]/2;
  const int ME = in_sizes[3]/2;
  const int NM = N + M;

  char* ws = (char*)d_ws;
  size_t off = 0;
  auto alloc = [&](size_t bytes)->void*{ void* p = ws + off; off += (bytes + 255) & ~(size_t)255; return p; };
  float* zbuf  = (float*)alloc((size_t)NM*64*4);            // concat(leaky(h3), mh)
  size_t hwords = (size_t)(2*N > NM ? 2*N : NM)*64;
  float* hreg  = (float*)alloc(hwords*4);                   // 2 rotating N x 64 buffers
  float* hA = hreg, *hB = hreg + (size_t)N*64;
  float* z2 = hreg;                                          // alias: meta gemm output (NM x 64)
  int*  ce_g = (int*)alloc((size_t)E*4);                    // CSR edges: src only (main)
  int*  ce_m = (int*)alloc((size_t)ME*4);                   // CSR edges: src only (meta)
  // zeroed region (one memset): cnt_g, cnt_m, cur_g, cur_m
  char* zero_base = ws + off;
  int* cnt_g    = (int*)alloc((size_t)N*4);
  int* cnt_m    = (int*)alloc((size_t)NM*4);
  int* cur_g    = (int*)alloc((size_t)N*4);
  int* cur_m    = (int*)alloc((size_t)NM*4);
  size_t zero_bytes = (ws + off) - zero_base;
  int* rowptr_g = (int*)alloc((size_t)(N+1)*4);
  int* rowptr_m = (int*)alloc((size_t)(NM+1)*4);
  int* bsumA    = (int*)alloc(1024*4);
  int* bsumB    = (int*)alloc(1024*4);
  float* dinv_g = (float*)alloc((size_t)N*4);
  float* dinv_m = (float*)alloc((size_t)NM*4);
  (void)ws_size; (void)n_in; (void)out_size;

  const int B = 256;
  const int nbA = cdiv(N, 256), nbB = cdiv(NM, 256);

  // zero counters (single memset node)
  (void)hipMemsetAsync(zero_base, 0, zero_bytes, stream);

  // degree histograms + dinv (self-loop => deg = cnt+1)
  k_count_dual<<<cdiv((long)E+ME,B), B, 0, stream>>>(ei+E, E, cnt_g, mei+ME, ME, cnt_m);
  k_dinv_dual<<<cdiv((long)N+NM,B), B, 0, stream>>>(cnt_g, dinv_g, N, cnt_m, dinv_m, NM);

  // CSR build (once; main CSR reused by all 3 layers)
  k_scan1_dual<<<nbA+nbB, 256, 0, stream>>>(cnt_g, rowptr_g, bsumA, N, nbA,
                                            cnt_m, rowptr_m, bsumB, NM);
  k_scan2_dual<<<1, 1024, 0, stream>>>(bsumA, nbA, bsumB, nbB);
  k_scan3_dual<<<nbA+nbB, 256, 0, stream>>>(rowptr_g, bsumA, N, nbA, E,
                                            rowptr_m, bsumB, NM, ME);
  k_fill_dual<<<cdiv((long)E+ME,B), B, 0, stream>>>(ei, E, rowptr_g, cur_g, ce_g,
                                                    mei, ME, rowptr_m, cur_m, ce_m);

  // input linears: h = leaky(x@W + b), fused epilogue
  k_gemm<128,0,1><<<1024, 256, 0, stream>>>(x,      W_lin,  b_lin,  hA,                 N);
  k_gemm<128,0,1><<<1024, 256, 0, stream>>>(meta_x, W_meta, b_meta, zbuf + (size_t)N*64, M);

  // 3 GCN layers on the main graph (2 rotating buffers)
  float* cin = hA; float* tmp = hB;
  for(int l=0; l<3; ++l){
    const float* Wl = Ws + (size_t)l*64*64;
    const float* bl = bs_ + (size_t)l*64;
    if(l==0) k_gemm<64,0,0><<<2048, 256, 0, stream>>>(cin, Wl, nullptr, tmp, N);
    else     k_gemm<64,1,0><<<2048, 256, 0, stream>>>(cin, Wl, nullptr, tmp, N);
    if(l<2) k_aggregate<0><<<cdiv(N,4), B, 0, stream>>>(tmp, rowptr_g, ce_g, dinv_g, bl, cin, N);
    else    k_aggregate<1><<<cdiv(N,4), B, 0, stream>>>(tmp, rowptr_g, ce_g, dinv_g, bl, zbuf, N);
  }

  // meta GCN over N+M nodes, classifier fused into the aggregate
  k_gemm<64,0,0><<<2048, 256, 0, stream>>>(zbuf, W_mg, nullptr, z2, NM);
  k_agg_cls<<<cdiv(NM,4), B, 0, stream>>>(z2, rowptr_m, ce_m, dinv_m, b_mg,
                                          W_cls, b_cls, out, NM);
}